// Round 1
// 229.184 us; speedup vs baseline: 1.1525x; 1.1525x over previous
//
#include <hip/hip_runtime.h>

typedef __bf16 bfrag __attribute__((ext_vector_type(8)));
typedef __bf16 bh4 __attribute__((ext_vector_type(4)));
typedef float f4 __attribute__((ext_vector_type(4)));

#define AS1C(p) (const __attribute__((address_space(1))) void*)(p)
#define AS3(p)  (__attribute__((address_space(3))) void*)(p)

// 0.125 (=1/sqrt(64)) * log2(e): folded into Q so softmax is a bare exp2
#define QSCALE 0.18033688011112042f

__device__ __forceinline__ void g2l16(const __bf16* g, __bf16* l) {
  __builtin_amdgcn_global_load_lds(AS1C(g), AS3(l), 16, 0, 0);
}

// ---------- f32 -> bf16 bulk convert: x + 4 weights in one dispatch ----------
__global__ __launch_bounds__(256) void cvt5(
    const float* __restrict__ s0, const float* __restrict__ s1,
    const float* __restrict__ s2, const float* __restrict__ s3,
    const float* __restrict__ s4,
    __bf16* __restrict__ d0, __bf16* __restrict__ d1, __bf16* __restrict__ d2,
    __bf16* __restrict__ d3, __bf16* __restrict__ d4, long n0, long n1) {
  const float* s; __bf16* d; long n;
  switch (blockIdx.y) {
    case 0: s = s0; d = d0; n = n0; break;
    case 1: s = s1; d = d1; n = n1; break;
    case 2: s = s2; d = d2; n = n1; break;
    case 3: s = s3; d = d3; n = n1; break;
    default: s = s4; d = d4; n = n1; break;
  }
  long i = ((long)blockIdx.x * 256 + threadIdx.x) * 8;
  if (i >= n) return;
  float4 a = *(const float4*)(s + i);
  float4 b = *(const float4*)(s + i + 4);
  bfrag o;
  o[0] = (__bf16)a.x; o[1] = (__bf16)a.y; o[2] = (__bf16)a.z; o[3] = (__bf16)a.w;
  o[4] = (__bf16)b.x; o[5] = (__bf16)b.y; o[6] = (__bf16)b.z; o[7] = (__bf16)b.w;
  *(bfrag*)(d + i) = o;
}

// ---------- fused QKV GEMM, BK=64 (two BK-32 substages per barrier) ----------
__global__ __launch_bounds__(256) void gemm_qkv(
    const __bf16* __restrict__ A, const __bf16* __restrict__ B,
    __bf16* __restrict__ qb, __bf16* __restrict__ kb, __bf16* __restrict__ vt,
    int M, int K) {
  __shared__ __bf16 sbuf[16640];  // k-loop: As0|As1|Bs0|Bs1; V-epi: 128x130
  __bf16* As0 = sbuf;
  __bf16* As1 = sbuf + 4096;
  __bf16* Bs0 = sbuf + 8192;
  __bf16* Bs1 = sbuf + 12288;
  const int tid = threadIdx.x;
  const int wave = tid >> 6, lane = tid & 63;
  const int lm = lane & 15, quad = lane >> 4;
  const int bm = blockIdx.x * 128, bn = blockIdx.y * 128;
  const int wr = (wave >> 1) * 64, wc = (wave & 1) * 64;
  f4 acc[4][4] = {};
  for (int k0 = 0; k0 < K; k0 += 64) {
#pragma unroll
    for (int ii = 0; ii < 2; ++ii) {
      int s = ii * 4 + wave;
      int e = s * 512 + lane * 8;
      int r = e >> 5, c = e & 31;
      const __bf16* ar = A + (long)(bm + r) * K + k0 + c;
      const __bf16* br = B + (long)(bn + r) * K + k0 + c;
      g2l16(ar, As0 + e);
      g2l16(ar + 32, As1 + e);
      g2l16(br, Bs0 + e);
      g2l16(br + 32, Bs1 + e);
    }
    __syncthreads();
#pragma unroll
    for (int st = 0; st < 2; ++st) {
      const __bf16* As = st ? As1 : As0;
      const __bf16* Bs = st ? Bs1 : Bs0;
      bfrag af[4], bg[4];
#pragma unroll
      for (int mi = 0; mi < 4; ++mi)
        af[mi] = *(const bfrag*)(As + (wr + mi * 16 + lm) * 32 + quad * 8);
#pragma unroll
      for (int ni = 0; ni < 4; ++ni)
        bg[ni] = *(const bfrag*)(Bs + (wc + ni * 16 + lm) * 32 + quad * 8);
#pragma unroll
      for (int mi = 0; mi < 4; ++mi)
#pragma unroll
        for (int ni = 0; ni < 4; ++ni)
          acc[mi][ni] = __builtin_amdgcn_mfma_f32_16x16x32_bf16(af[mi], bg[ni], acc[mi][ni], 0, 0, 0);
    }
    __syncthreads();
  }
  if (bn < 2048) {
    __bf16* dst = (bn < 1024) ? qb : kb;
    const float scl = (bn < 1024) ? QSCALE : 1.0f;
    const int nb = bn & 1023;
#pragma unroll
    for (int mi = 0; mi < 4; ++mi)
#pragma unroll
      for (int ni = 0; ni < 4; ++ni)
#pragma unroll
        for (int r = 0; r < 4; ++r) {
          long row = bm + wr + mi * 16 + quad * 4 + r;
          long col = nb + wc + ni * 16 + lm;
          dst[row * 1024 + col] = (__bf16)(acc[mi][ni][r] * scl);
        }
  } else {
    // V: acc(row=t, col=d) -> vt[d][t'], t' = (t>>6)*64 + kappa'(t&63)
#pragma unroll
    for (int mi = 0; mi < 4; ++mi)
#pragma unroll
      for (int ni = 0; ni < 4; ++ni)
#pragma unroll
        for (int r = 0; r < 4; ++r) {
          int d = wc + ni * 16 + lm;
          int tp = (wr ? 64 : 0) + (quad * 4 + r) * 4 + mi;
          sbuf[d * 130 + tp] = (__bf16)acc[mi][ni][r];
        }
    __syncthreads();
    const int bloc = bm >> 11;
    const int tloc = bm & 2047;
#pragma unroll
    for (int p = 0; p < 8; ++p) {
      int d = (tid >> 4) + p * 16;
      int c = (tid & 15) * 8;
      long dglob = (bn - 2048) + d;
      *(bfrag*)(vt + ((long)bloc * 1024 + dglob) * 2048 + tloc + c) =
          *(const bfrag*)(sbuf + d * 130 + c);
    }
  }
}

// ---------- plain GEMM (bf16 in), BK=64, final projection ----------
template <bool OUT_F32>
__global__ __launch_bounds__(256) void gemm_bt_bf16(
    const __bf16* __restrict__ A, const __bf16* __restrict__ B,
    void* __restrict__ Cp, int M, int N, int K) {
  __shared__ __bf16 sbuf[16384];
  __bf16* As0 = sbuf;
  __bf16* As1 = sbuf + 4096;
  __bf16* Bs0 = sbuf + 8192;
  __bf16* Bs1 = sbuf + 12288;
  const int tid = threadIdx.x;
  const int wave = tid >> 6, lane = tid & 63;
  const int lm = lane & 15, quad = lane >> 4;
  const int bm = blockIdx.x * 128, bn = blockIdx.y * 128;
  const int wr = (wave >> 1) * 64, wc = (wave & 1) * 64;
  f4 acc[4][4] = {};
  for (int k0 = 0; k0 < K; k0 += 64) {
#pragma unroll
    for (int ii = 0; ii < 2; ++ii) {
      int s = ii * 4 + wave;
      int e = s * 512 + lane * 8;
      int r = e >> 5, c = e & 31;
      const __bf16* ar = A + (long)(bm + r) * K + k0 + c;
      const __bf16* br = B + (long)(bn + r) * K + k0 + c;
      g2l16(ar, As0 + e);
      g2l16(ar + 32, As1 + e);
      g2l16(br, Bs0 + e);
      g2l16(br + 32, Bs1 + e);
    }
    __syncthreads();
#pragma unroll
    for (int st = 0; st < 2; ++st) {
      const __bf16* As = st ? As1 : As0;
      const __bf16* Bs = st ? Bs1 : Bs0;
      bfrag af[4], bg[4];
#pragma unroll
      for (int mi = 0; mi < 4; ++mi)
        af[mi] = *(const bfrag*)(As + (wr + mi * 16 + lm) * 32 + quad * 8);
#pragma unroll
      for (int ni = 0; ni < 4; ++ni)
        bg[ni] = *(const bfrag*)(Bs + (wc + ni * 16 + lm) * 32 + quad * 8);
#pragma unroll
      for (int mi = 0; mi < 4; ++mi)
#pragma unroll
        for (int ni = 0; ni < 4; ++ni)
          acc[mi][ni] = __builtin_amdgcn_mfma_f32_16x16x32_bf16(af[mi], bg[ni], acc[mi][ni], 0, 0, 0);
    }
    __syncthreads();
  }
#pragma unroll
  for (int mi = 0; mi < 4; ++mi)
#pragma unroll
    for (int ni = 0; ni < 4; ++ni)
#pragma unroll
      for (int r = 0; r < 4; ++r) {
        long row = bm + wr + mi * 16 + quad * 4 + r;
        long col = bn + wc + ni * 16 + lm;
        if (OUT_F32) ((float*)Cp)[row * N + col] = acc[mi][ni][r];
        else ((__bf16*)Cp)[row * N + col] = (__bf16)acc[mi][ni][r];
      }
}

// ---------- fallback GEMM (f32 A / f32 B, inline convert) ----------
template <bool A_F32, bool OUT_F32>
__global__ __launch_bounds__(256) void gemm_bt_cv(
    const void* __restrict__ Ap, const float* __restrict__ Bp,
    void* __restrict__ Cp, int M, int N, int K, float scl) {
  __shared__ __bf16 As[128 * 32];
  __shared__ __bf16 Bs[128 * 32];
  const int tid = threadIdx.x;
  const int lane = tid & 63, wave = tid >> 6;
  const int lm = lane & 15, quad = lane >> 4;
  const int bm = blockIdx.x * 128, bn = blockIdx.y * 128;
  const int wr = (wave >> 1) * 64, wc = (wave & 1) * 64;
  const int e0 = tid * 16, sr = e0 >> 5, sc = e0 & 31;
  f4 acc[4][4] = {};
  for (int k0 = 0; k0 < K; k0 += 32) {
    if (A_F32) {
      const float4* ga = (const float4*)((const float*)Ap + (long)(bm + sr) * K + k0 + sc);
#pragma unroll
      for (int j = 0; j < 4; ++j) {
        float4 v = ga[j];
        As[sr * 32 + sc + j * 4 + 0] = (__bf16)v.x;
        As[sr * 32 + sc + j * 4 + 1] = (__bf16)v.y;
        As[sr * 32 + sc + j * 4 + 2] = (__bf16)v.z;
        As[sr * 32 + sc + j * 4 + 3] = (__bf16)v.w;
      }
    } else {
      const __bf16* Ab = (const __bf16*)Ap + (long)(bm + sr) * K + k0 + sc;
      *(bfrag*)(As + sr * 32 + sc) = *(const bfrag*)Ab;
      *(bfrag*)(As + sr * 32 + sc + 8) = *(const bfrag*)(Ab + 8);
    }
    {
      const float4* gb = (const float4*)(Bp + (long)(bn + sr) * K + k0 + sc);
#pragma unroll
      for (int j = 0; j < 4; ++j) {
        float4 v = gb[j];
        Bs[sr * 32 + sc + j * 4 + 0] = (__bf16)v.x;
        Bs[sr * 32 + sc + j * 4 + 1] = (__bf16)v.y;
        Bs[sr * 32 + sc + j * 4 + 2] = (__bf16)v.z;
        Bs[sr * 32 + sc + j * 4 + 3] = (__bf16)v.w;
      }
    }
    __syncthreads();
    bfrag af[4], bg[4];
#pragma unroll
    for (int mi = 0; mi < 4; ++mi)
      af[mi] = *(const bfrag*)(As + (wr + mi * 16 + lm) * 32 + quad * 8);
#pragma unroll
    for (int ni = 0; ni < 4; ++ni)
      bg[ni] = *(const bfrag*)(Bs + (wc + ni * 16 + lm) * 32 + quad * 8);
#pragma unroll
    for (int mi = 0; mi < 4; ++mi)
#pragma unroll
      for (int ni = 0; ni < 4; ++ni)
        acc[mi][ni] = __builtin_amdgcn_mfma_f32_16x16x32_bf16(af[mi], bg[ni], acc[mi][ni], 0, 0, 0);
    __syncthreads();
  }
#pragma unroll
  for (int mi = 0; mi < 4; ++mi)
#pragma unroll
    for (int ni = 0; ni < 4; ++ni)
#pragma unroll
      for (int r = 0; r < 4; ++r) {
        long row = bm + wr + mi * 16 + quad * 4 + r;
        long col = bn + wc + ni * 16 + lm;
        if (OUT_F32) ((float*)Cp)[row * N + col] = acc[mi][ni][r] * scl;
        else ((__bf16*)Cp)[row * N + col] = (__bf16)(acc[mi][ni][r] * scl);
      }
}

// ---------- flash attention v8: 128-row q-tiles, 4 frags/wave ----------
// Each wave owns four 16-row fragments: rows {qtA*128, qtA*128+64,
// qtB*128, qtB*128+64} + wave*16, with qtA = i, qtB = 15-i (balanced:
// 66 active frag-iters per wave for every i). One K/V stage per 64-k
// tile serves all four fragments -> kf/vf LDS re-reads per FLOP halved,
// staging + barrier count halved vs v7. T14: next-tile global loads
// issued under current-tile compute. All activity/diag branches are
// wave-uniform (row0 mod 64 = wave*16 < 64-boundary).
#define KP 72

template <bool VT>
__global__ __launch_bounds__(256, 2) void attn_fwd8(
    const __bf16* Qg, const __bf16* __restrict__ Kg,
    const __bf16* __restrict__ Vsrc, __bf16* Yg) {
  const int TT = 2048, CC = 1024;
  __shared__ __bf16 Ks[64 * KP];       // 9216 B
  __shared__ __bf16 Vs[64 * KP];       // 9216 B  (V^T kappa': [d][kp])
  __shared__ __bf16 Ps[16 * 16 * KP];  // 36864 B: 4 waves x 4 frag regions
  const int tid = threadIdx.x;
  const int wave = tid >> 6, lane = tid & 63;
  const int lm = lane & 15, quad = lane >> 4;
  // grid: x = b*16+h (64), y = i (8)  -> same-bh blocks share an XCD (L2)
  const int bh = blockIdx.x, i = blockIdx.y;
  const int b = bh >> 4, h = bh & 15;
  const int qtA = i, qtB = 15 - i;
  const long rbase = (long)b * TT;
  const int hoff = h * 64;
  int row0[4];
  row0[0] = qtA * 128 + wave * 16;
  row0[1] = qtA * 128 + 64 + wave * 16;
  row0[2] = qtB * 128 + wave * 16;
  row0[3] = qtB * 128 + 64 + wave * 16;
  __bf16* Pw[4];
#pragma unroll
  for (int fr = 0; fr < 4; ++fr) Pw[fr] = Ps + (wave * 4 + fr) * 16 * KP;
  bfrag qf[4][2];
#pragma unroll
  for (int fr = 0; fr < 4; ++fr)
#pragma unroll
    for (int f = 0; f < 2; ++f)
      qf[fr][f] = *(const bfrag*)(Qg + (rbase + row0[fr] + lm) * CC + hoff + f * 32 + quad * 8);
  bfrag ones;
#pragma unroll
  for (int j = 0; j < 8; ++j) ones[j] = (__bf16)1.0f;
  f4 y[4][4] = {};
  f4 L[4] = {};

  const int ktLast = 2 * qtB + 1;
  // prologue: load tile 0 into regs
  bfrag kin[2], vin[2];
#pragma unroll
  for (int s = 0; s < 2; ++s) {
    int idx = tid + s * 256;
    int r = idx >> 3, c = (idx & 7) * 8;
    kin[s] = *(const bfrag*)(Kg + (rbase + r) * CC + hoff + c);
    if (VT)
      vin[s] = *(const bfrag*)(Vsrc + ((long)b * 1024 + hoff + r) * 2048 + c);
    else
      vin[s] = *(const bfrag*)(Vsrc + (rbase + r) * CC + hoff + c);
  }

  for (int kt = 0; kt <= ktLast; ++kt) {
    const int kBase = kt * 64;
    __syncthreads();
    // write staged regs -> LDS
#pragma unroll
    for (int s = 0; s < 2; ++s) {
      int idx = tid + s * 256;
      int r = idx >> 3, c = (idx & 7) * 8;
      *(bfrag*)(Ks + r * KP + c) = kin[s];
      if (VT) {
        *(bfrag*)(Vs + r * KP + c) = vin[s];
      } else {
        int kp = (r & 15) * 4 + (r >> 4);
#pragma unroll
        for (int j = 0; j < 8; ++j) Vs[(c + j) * KP + kp] = vin[s][j];
      }
    }
    // T14: issue next-tile global loads now; they complete under compute
    const bool more = (kt < ktLast);
    bfrag kin2[2], vin2[2];
    if (more) {
      const int nB = kBase + 64;
#pragma unroll
      for (int s = 0; s < 2; ++s) {
        int idx = tid + s * 256;
        int r = idx >> 3, c = (idx & 7) * 8;
        kin2[s] = *(const bfrag*)(Kg + (rbase + nB + r) * CC + hoff + c);
        if (VT)
          vin2[s] = *(const bfrag*)(Vsrc + ((long)b * 1024 + hoff + r) * 2048 + nB + c);
        else
          vin2[s] = *(const bfrag*)(Vsrc + (rbase + nB + r) * CC + hoff + c);
      }
    }
    __syncthreads();
    // K fragments (shared by all 4 q-fragments)
    bfrag kf[8];
#pragma unroll
    for (int sub = 0; sub < 4; ++sub)
#pragma unroll
      for (int f = 0; f < 2; ++f)
        kf[sub * 2 + f] = *(const bfrag*)(Ks + (sub * 16 + lm) * KP + f * 32 + quad * 8);
    // phase 1: QK^T + exp2 + P write, per active fragment
#pragma unroll
    for (int fr = 0; fr < 4; ++fr) {
      if (kBase <= row0[fr] + 15) {   // wave-uniform
        f4 sac[4];
#pragma unroll
        for (int sub = 0; sub < 4; ++sub) {
          f4 z = {};
#pragma unroll
          for (int f = 0; f < 2; ++f)
            z = __builtin_amdgcn_mfma_f32_16x16x32_bf16(qf[fr][f], kf[sub * 2 + f], z, 0, 0, 0);
          sac[sub] = z;
        }
        if (kBase + 63 > row0[fr]) {  // diagonal tile (wave-uniform)
#pragma unroll
          for (int r = 0; r < 4; ++r) {
            bh4 pk;
#pragma unroll
            for (int sub = 0; sub < 4; ++sub) {
              float pv = __builtin_amdgcn_exp2f(sac[sub][r]);
              bool masked = (kBase + sub * 16 + lm > row0[fr] + quad * 4 + r);
              pk[sub] = (__bf16)(masked ? 0.f : pv);
            }
            *(bh4*)(Pw[fr] + (quad * 4 + r) * KP + lm * 4) = pk;
          }
        } else {
#pragma unroll
          for (int r = 0; r < 4; ++r) {
            bh4 pk;
#pragma unroll
            for (int sub = 0; sub < 4; ++sub)
              pk[sub] = (__bf16)__builtin_amdgcn_exp2f(sac[sub][r]);
            *(bh4*)(Pw[fr] + (quad * 4 + r) * KP + lm * 4) = pk;
          }
        }
      }
    }
    __asm__ volatile("s_waitcnt lgkmcnt(0)" ::: "memory");
    // V fragments (kf dead here -> register lifetime handoff)
    bfrag vf[8];
#pragma unroll
    for (int sub = 0; sub < 4; ++sub)
#pragma unroll
      for (int f = 0; f < 2; ++f)
        vf[sub * 2 + f] = *(const bfrag*)(Vs + (sub * 16 + lm) * KP + f * 32 + quad * 8);
    // phase 2: PV + L, per active fragment
#pragma unroll
    for (int fr = 0; fr < 4; ++fr) {
      if (kBase <= row0[fr] + 15) {
#pragma unroll
        for (int f = 0; f < 2; ++f) {
          bfrag pf = *(const bfrag*)(Pw[fr] + lm * KP + f * 32 + quad * 8);
          L[fr] = __builtin_amdgcn_mfma_f32_16x16x32_bf16(pf, ones, L[fr], 0, 0, 0);
#pragma unroll
          for (int ds = 0; ds < 4; ++ds)
            y[fr][ds] = __builtin_amdgcn_mfma_f32_16x16x32_bf16(pf, vf[ds * 2 + f], y[fr][ds], 0, 0, 0);
        }
      }
    }
    if (more) {
      kin[0] = kin2[0]; kin[1] = kin2[1];
      vin[0] = vin2[0]; vin[1] = vin2[1];
    }
  }
#pragma unroll
  for (int fr = 0; fr < 4; ++fr)
#pragma unroll
    for (int ds = 0; ds < 4; ++ds)
#pragma unroll
      for (int r = 0; r < 4; ++r) {
        long row = rbase + row0[fr] + quad * 4 + r;
        Yg[row * CC + hoff + ds * 16 + lm] = (__bf16)(y[fr][ds][r] / L[fr][r]);
      }
}

extern "C" void kernel_launch(void* const* d_in, const int* in_sizes, int n_in,
                              void* d_out, int out_size, void* d_ws, size_t ws_size,
                              hipStream_t stream) {
  (void)in_sizes; (void)n_in; (void)out_size;
  const float* x  = (const float*)d_in[0];
  const float* Wq = (const float*)d_in[1];
  const float* Wk = (const float*)d_in[2];
  const float* Wv = (const float*)d_in[3];
  const float* Wp = (const float*)d_in[4];
  float* out = (float*)d_out;
  const long R = 8192;             // B*T
  const long BUF = R * 1024;
  const long WN = 1024L * 1024;
  __bf16* qb = (__bf16*)d_ws;      // q (pre-scaled), then y in-place
  __bf16* kb = (__bf16*)d_out;     // k + vt borrow d_out (dead before final GEMM)
  __bf16* vslot = kb + BUF;
  dim3 blk(256, 1, 1);
  const size_t need = (size_t)(2 * BUF + 4 * WN) * 2;
  if (ws_size >= need) {
    __bf16* xb = qb + BUF;
    __bf16* wqkv = xb + BUF;       // Wq,Wk,Wv contiguous = [3072][1024]
    __bf16* wpb = wqkv + 3 * WN;
    cvt5<<<dim3((unsigned)(BUF / (256 * 8)), 5, 1), blk, 0, stream>>>(
        x, Wq, Wk, Wv, Wp, xb, wqkv, wqkv + WN, wqkv + 2 * WN, wpb, BUF, WN);
    gemm_qkv<<<dim3(64, 24, 1), blk, 0, stream>>>(xb, wqkv, qb, kb, vslot, 8192, 1024);
    attn_fwd8<true><<<dim3(64, 8, 1), blk, 0, stream>>>(qb, kb, vslot, qb);
    gemm_bt_bf16<true><<<dim3(64, 8, 1), blk, 0, stream>>>(qb, wpb, out, 8192, 1024, 1024);
  } else {
    gemm_bt_cv<true, false><<<dim3(64, 8, 1), blk, 0, stream>>>(x, Wq, qb, 8192, 1024, 1024, QSCALE);
    gemm_bt_cv<true, false><<<dim3(64, 8, 1), blk, 0, stream>>>(x, Wk, kb, 8192, 1024, 1024, 1.0f);
    gemm_bt_cv<true, false><<<dim3(64, 8, 1), blk, 0, stream>>>(x, Wv, vslot, 8192, 1024, 1024, 1.0f);
    attn_fwd8<false><<<dim3(64, 8, 1), blk, 0, stream>>>(qb, kb, vslot, qb);
    gemm_bt_cv<false, true><<<dim3(64, 8, 1), blk, 0, stream>>>(qb, Wp, out, 8192, 1024, 1024, 1.0f);
  }
}